// Round 5
// baseline (7821.449 us; speedup 1.0000x reference)
//
#include <hip/hip_runtime.h>
#include <hip/hip_bf16.h>
#include <math.h>

// Problem constants (match reference)
#define BB 4
#define PP 32768
#define TOPK 5000
#define NB 4096          // score buckets for ranking
#define ECAP 104448      // edge capacity per image (edges alias phase-1 bufs)
#define NBK 20           // ceil(5000/256) candidate tiles
#define TBPI 210         // NBK*(NBK+1)/2 triangular tile pairs per image
#define NWRD 157         // ceil(5000/32) alive-mask words (fallback path)

// ws layout (bytes). Total 3,742,592 <= 3,742,720 B PROVEN available (round 1
// passed with its guard at exactly 3,742,720).
// Phase 1 (ranking): hist/start/cnt/gidx/gscore live at PH1.
// Phase 2 (NMS): the edge array ALIASES the whole phase-1 region (dead by then).
#define NV_OFF     0u
#define NC_OFF     64u
#define ECNT_OFF   128u         // uint[BB], memset 64B each launch
#define CS_OFF     256u         // float[BB*TOPK]  = 80,000
#define CB_OFF     80256u       // float4[BB*TOPK] = 320,000
#define PH1_OFF    400256u
#define HIST_OFF   400256u      // uint[BB*NB] = 65,536
#define START_OFF  465792u      // uint[BB*NB] = 65,536
#define CNT_OFF    531328u      // uint[BB*NB] = 65,536
#define GIDX_OFF   596864u      // uint[BB*PP] = 524,288
#define GSC_OFF    1121152u     // float[BB*PP]= 524,288  (ends 1,645,440)
#define EDGE_OFF   400256u      // uint2[BB*ECAP] = 3,342,336 (ends 3,742,592)
#define WS_NEEDED  3742720u

__global__ __launch_bounds__(256) void score_hist_kernel(
    const float2* __restrict__ conf, unsigned* __restrict__ hist)
{
    int i = blockIdx.x * 256 + threadIdx.x;
    if (i >= BB * PP) return;
    int b = i >> 15;
    float s = conf[i].y;
    if (s > 0.05f) {
        int bk = (int)(s * 4096.0f);
        bk = bk < 0 ? 0 : (bk > NB - 1 ? NB - 1 : bk);
        atomicAdd(&hist[b * NB + bk], 1u);
    }
}

__global__ __launch_bounds__(256) void scan_hist_kernel(
    const unsigned* __restrict__ hist, unsigned* __restrict__ start,
    int* __restrict__ nvalid, int* __restrict__ ncand)
{
    int b = blockIdx.x;
    int t = threadIdx.x;
    __shared__ unsigned sums[256];
    unsigned local[16];
    unsigned s = 0;
    const unsigned* hb = hist + b * NB;
    #pragma unroll
    for (int k = 0; k < 16; k++) {
        unsigned v = hb[t * 16 + k];
        local[k] = s;
        s += v;
    }
    sums[t] = s;
    __syncthreads();
    for (int off = 1; off < 256; off <<= 1) {
        unsigned v = (t >= off) ? sums[t - off] : 0u;
        __syncthreads();
        sums[t] += v;
        __syncthreads();
    }
    unsigned excl = sums[t] - s;
    unsigned* sb = start + b * NB;
    #pragma unroll
    for (int k = 0; k < 16; k++) sb[t * 16 + k] = excl + local[k];
    if (t == 255) {
        nvalid[b] = (int)sums[255];
        ncand[b] = sums[255] < (unsigned)TOPK ? (int)sums[255] : TOPK;
    }
}

__global__ __launch_bounds__(256) void scatter_group_kernel(
    const float2* __restrict__ conf, const unsigned* __restrict__ start,
    unsigned* __restrict__ cnt, unsigned* __restrict__ gidx,
    float* __restrict__ gscore)
{
    int i = blockIdx.x * 256 + threadIdx.x;
    if (i >= BB * PP) return;
    int b = i >> 15;
    int p = i & (PP - 1);
    float s = conf[i].y;
    if (s > 0.05f) {
        int bk = (int)(s * 4096.0f);
        bk = bk < 0 ? 0 : (bk > NB - 1 ? NB - 1 : bk);
        unsigned o = atomicAdd(&cnt[b * NB + bk], 1u);
        unsigned pos = start[b * NB + bk] + o;
        gidx[b * PP + pos] = (unsigned)p;
        gscore[b * PP + pos] = s;
    }
}

// Exact stable rank (bucket base + within-bucket compare); decode the box
// with the identical fp expressions the (passing) round-1 decode used.
__global__ __launch_bounds__(256) void rank_topk_kernel(
    const unsigned* __restrict__ gidx, const float* __restrict__ gscore,
    const unsigned* __restrict__ start, const unsigned* __restrict__ hist,
    const int* __restrict__ nvalid, const float4* __restrict__ loc,
    const float4* __restrict__ prior,
    float* __restrict__ cs, float4* __restrict__ cb)
{
#pragma clang fp contract(off)
    int i = blockIdx.x * 256 + threadIdx.x;
    if (i >= BB * PP) return;
    int b = i >> 15;
    int pos = i & (PP - 1);
    int nv = nvalid[b];
    if (pos >= nv) return;
    float s = gscore[b * PP + pos];
    unsigned p = gidx[b * PP + pos];
    int bk = (int)(s * 4096.0f);
    bk = bk < 0 ? 0 : (bk > NB - 1 ? NB - 1 : bk);
    unsigned st = start[b * NB + bk];
    unsigned c = hist[b * NB + bk];
    unsigned rank = (unsigned)nv - st - c;   // strictly-higher buckets
    const float* gs = gscore + b * PP + st;
    const unsigned* gi = gidx + b * PP + st;
    for (unsigned k = 0; k < c; k++) {
        float sk = gs[k];
        unsigned pk = gi[k];
        if (sk > s || (sk == s && pk < p)) rank++;   // stable descending
    }
    if (rank < (unsigned)TOPK) {
        float4 l = loc[b * PP + (int)p];
        float4 pr = prior[p];
        float cx = pr.x + (l.x * 0.1f) * pr.z;
        float cy = pr.y + (l.y * 0.1f) * pr.w;
        float w = pr.z * expf(l.z * 0.2f);
        float h = pr.w * expf(l.w * 0.2f);
        float4 bx;
        bx.x = cx - 0.5f * w;
        bx.y = cy - 0.5f * h;
        bx.z = cx + 0.5f * w;
        bx.w = cy + 0.5f * h;
        cs[b * TOPK + rank] = s;
        cb[(size_t)b * TOPK + rank] = bx;
    }
}

// All-pairs IoU over candidates; emit sparse suppression edges (j<i).
// ecnt counts ALL edges (even past capacity) so solve can detect overflow.
__global__ __launch_bounds__(256) void pair_kernel(
    const float4* __restrict__ cb, const int* __restrict__ ncand,
    unsigned* __restrict__ ecnt, uint2* __restrict__ edges)
{
#pragma clang fp contract(off)
    int b = blockIdx.x / TBPI;
    int t_ = blockIdx.x % TBPI;
    int bi = (int)((sqrtf(8.0f * (float)t_ + 1.0f) - 1.0f) * 0.5f);
    while ((bi + 1) * (bi + 2) / 2 <= t_) bi++;
    while (bi * (bi + 1) / 2 > t_) bi--;
    int bj = t_ - bi * (bi + 1) / 2;

    int nc = ncand[b];
    const float4* cbb = cb + (size_t)b * TOPK;

    __shared__ float4 jb[256];
    __shared__ float ja[256];
    int tid = threadIdx.x;
    int jg = bj * 256 + tid;
    if (jg < nc) {
        float4 v = cbb[jg];
        jb[tid] = v;
        ja[tid] = (v.z - v.x) * (v.w - v.y);
    }
    __syncthreads();

    int i = bi * 256 + tid;
    if (i >= nc) return;
    float4 bx = cbb[i];
    float areaI = (bx.z - bx.x) * (bx.w - bx.y);

    int jmax = nc - bj * 256;
    jmax = jmax > 256 ? 256 : jmax;
    if (bi == bj) { int lim = i - bj * 256; jmax = jmax < lim ? jmax : lim; }

    for (int k = 0; k < jmax; k++) {
        float4 c = jb[k];
        float iw = fminf(bx.z, c.z) - fmaxf(bx.x, c.x);
        iw = fmaxf(iw, 0.0f);
        float ih = fminf(bx.w, c.w) - fmaxf(bx.y, c.y);
        ih = fmaxf(ih, 0.0f);
        float inter = iw * ih;
        float uni = (ja[k] + areaI) - inter;   // area[j] + area[i] - inter
        if (inter / uni > 0.3f) {              // NaN -> false, matches jnp
            unsigned pos = atomicAdd(&ecnt[b], 1u);
            if (pos < ECAP)
                edges[(size_t)b * ECAP + pos] = make_uint2((unsigned)(bj * 256 + k),
                                                           (unsigned)i);
        }
    }
}

// Fast path: round-based fixpoint on the sparse edge list (order-independent).
// Fallback (ecnt > ECAP): the round-1 serial greedy NMS, proven absmax 0.0.
__global__ __launch_bounds__(1024) void solve_kernel(
    const float* __restrict__ cs, const float4* __restrict__ cb,
    const int* __restrict__ ncand, const unsigned* __restrict__ ecnt,
    const uint2* __restrict__ edges, float* __restrict__ out)
{
#pragma clang fp contract(off)
    int b = blockIdx.x;
    int t = threadIdx.x;
    int nc = ncand[b];
    unsigned ne = ecnt[b];
    const float* csb = cs + b * TOPK;
    const float4* cbb = cb + (size_t)b * TOPK;
    float* outb = out + ((size_t)b * 2 + 1) * TOPK * 5;

    if (ne <= (unsigned)ECAP) {
        // ---------- fast path: edge fixpoint ----------
        __shared__ unsigned char state[5120];   // 0=undecided 1=kept 2=dead
        __shared__ unsigned char dead[5120];
        __shared__ unsigned char blocked[5120];
        __shared__ int nundec;
        __shared__ uint2 ledge[8192];           // LDS edge cache when small
        __shared__ unsigned wsum[16];
        __shared__ unsigned wbase[16];

        const uint2* E = edges + (size_t)b * ECAP;
        bool inl = (ne <= 8192u);
        if (inl) for (unsigned e = t; e < ne; e += 1024) ledge[e] = E[e];
        for (int i = t; i < 5120; i += 1024) state[i] = (i < nc) ? 0 : 2;
        if (t == 0) nundec = nc;
        __syncthreads();
        const uint2* ES = inl ? (const uint2*)ledge : E;

        for (int round = 0; round <= TOPK && nundec > 0; ++round) {
            for (int i = t; i < nc; i += 1024) { dead[i] = 0; blocked[i] = 0; }
            __syncthreads();
            for (unsigned e = t; e < ne; e += 1024) {
                uint2 ed = ES[e];
                unsigned char sj = state[ed.x];
                if (sj == 1) dead[ed.y] = 1;
                else if (sj == 0) blocked[ed.y] = 1;
            }
            __syncthreads();
            for (int i = t; i < nc; i += 1024) {
                if (state[i] == 0) {
                    if (dead[i])          { state[i] = 2; atomicSub(&nundec, 1); }
                    else if (!blocked[i]) { state[i] = 1; atomicSub(&nundec, 1); }
                }
            }
            __syncthreads();
        }

        // compact kept candidates in order, write output rows
        int base = t * 5;
        int keep[5];
        int cnt = 0;
        #pragma unroll
        for (int k = 0; k < 5; k++) {
            int i = base + k;
            int kp = (i < nc && state[i] == 1) ? 1 : 0;
            keep[k] = kp;
            cnt += kp;
        }
        int lane = t & 63, wv = t >> 6;
        int v = cnt;
        for (int off = 1; off < 64; off <<= 1) {
            int u = __shfl_up(v, off);
            if (lane >= off) v += u;
        }
        if (lane == 63) wsum[wv] = (unsigned)v;
        __syncthreads();
        if (t == 0) {
            unsigned s = 0;
            for (int w = 0; w < 16; w++) { wbase[w] = s; s += wsum[w]; }
        }
        __syncthreads();
        unsigned pos = wbase[wv] + (unsigned)(v - cnt);
        #pragma unroll
        for (int k = 0; k < 5; k++) {
            int i = base + k;
            if (keep[k]) {
                float4 bx = cbb[i];
                float* row = outb + (size_t)pos * 5;
                row[0] = csb[i];
                row[1] = bx.x;
                row[2] = bx.y;
                row[3] = bx.z;
                row[4] = bx.w;
                pos++;
            }
        }
    } else {
        // ---------- fallback: serial greedy NMS (round-1 proven) ----------
        __shared__ unsigned alive[NWRD];
        __shared__ int jslot;
        __shared__ int kslot;
        for (int w = t; w < NWRD; w += 1024) {
            int lo = w * 32;
            unsigned m = 0u;
            if (lo + 32 <= nc) m = 0xffffffffu;
            else if (lo < nc) m = (1u << (nc - lo)) - 1u;
            alive[w] = m;
        }
        if (t == 0) kslot = 0;
        __syncthreads();

        for (int iter = 0; iter <= TOPK; iter++) {
            if (t < 64) {
                unsigned a0 = alive[t];
                unsigned a1 = (t + 64 < NWRD) ? alive[t + 64] : 0u;
                unsigned a2 = (t + 128 < NWRD) ? alive[t + 128] : 0u;
                unsigned long long b0 = __ballot(a0 != 0u);
                unsigned long long b1 = __ballot(a1 != 0u);
                unsigned long long b2 = __ballot(a2 != 0u);
                int j = -1;
                int w = -1;
                if (b0) w = (int)__builtin_ctzll(b0);
                else if (b1) w = 64 + (int)__builtin_ctzll(b1);
                else if (b2) w = 128 + (int)__builtin_ctzll(b2);
                if (w >= 0) {
                    unsigned aw = alive[w];
                    j = w * 32 + (int)__builtin_ctz(aw);
                }
                if (t == 0) jslot = j;
            }
            __syncthreads();
            int j = jslot;
            if (j < 0) break;

            float4 bj = cbb[j];
            if (t == 0) {
                float sj = csb[j];
                int k = kslot++;
                float* row = outb + (size_t)k * 5;
                row[0] = sj;
                row[1] = bj.x;
                row[2] = bj.y;
                row[3] = bj.z;
                row[4] = bj.w;
                alive[j >> 5] &= ~(1u << (j & 31));  // self-clear
            }
            __syncthreads();

            float ax1 = bj.x, ay1 = bj.y, ax2 = bj.z, ay2 = bj.w;
            float areaj = (ax2 - ax1) * (ay2 - ay1);
            for (int c = t; c < TOPK; c += 1024) {
                float4 bc = cbb[c];
                float iw = fminf(ax2, bc.z) - fmaxf(ax1, bc.x);
                iw = fmaxf(iw, 0.0f);
                float ih = fminf(ay2, bc.w) - fmaxf(ay1, bc.y);
                ih = fmaxf(ih, 0.0f);
                float inter = iw * ih;
                float areac = (bc.z - bc.x) * (bc.w - bc.y);
                float uni = areaj + areac - inter;
                bool sup = (inter / uni) > 0.3f;
                unsigned long long m = __ballot(sup);
                int lane = t & 63;
                int base = c - lane;
                if (lane == 0)  alive[(base >> 5)]     &= ~(unsigned)(m & 0xffffffffull);
                if (lane == 32) alive[(base >> 5) + 1] &= ~(unsigned)(m >> 32);
            }
            __syncthreads();
        }
    }
}

extern "C" void kernel_launch(void* const* d_in, const int* in_sizes, int n_in,
                              void* d_out, int out_size, void* d_ws, size_t ws_size,
                              hipStream_t stream) {
    if (ws_size < WS_NEEDED) return;  // fail loudly rather than corrupt

    const float4* loc = (const float4*)d_in[0];
    const float2* conf = (const float2*)d_in[1];
    const float4* prior = (const float4*)d_in[2];
    float* out = (float*)d_out;

    char* ws = (char*)d_ws;
    int* nvalid = (int*)(ws + NV_OFF);
    int* ncand = (int*)(ws + NC_OFF);
    unsigned* ecnt = (unsigned*)(ws + ECNT_OFF);
    float* cs = (float*)(ws + CS_OFF);
    float4* cb = (float4*)(ws + CB_OFF);
    unsigned* hist = (unsigned*)(ws + HIST_OFF);
    unsigned* start = (unsigned*)(ws + START_OFF);
    unsigned* cnt = (unsigned*)(ws + CNT_OFF);
    unsigned* gidx = (unsigned*)(ws + GIDX_OFF);
    float* gscore = (float*)(ws + GSC_OFF);
    uint2* edges = (uint2*)(ws + EDGE_OFF);   // aliases phase-1 region (dead)

    hipMemsetAsync(d_out, 0, (size_t)out_size * sizeof(float), stream);
    hipMemsetAsync(hist, 0, (size_t)BB * NB * sizeof(unsigned), stream);
    hipMemsetAsync(cnt, 0, (size_t)BB * NB * sizeof(unsigned), stream);
    hipMemsetAsync(ecnt, 0, 64, stream);

    int nblk = (BB * PP + 255) / 256;
    score_hist_kernel<<<nblk, 256, 0, stream>>>(conf, hist);
    scan_hist_kernel<<<BB, 256, 0, stream>>>(hist, start, nvalid, ncand);
    scatter_group_kernel<<<nblk, 256, 0, stream>>>(conf, start, cnt, gidx, gscore);
    rank_topk_kernel<<<nblk, 256, 0, stream>>>(gidx, gscore, start, hist, nvalid,
                                               loc, prior, cs, cb);
    pair_kernel<<<BB * TBPI, 256, 0, stream>>>(cb, ncand, ecnt, edges);
    solve_kernel<<<BB, 1024, 0, stream>>>(cs, cb, ncand, ecnt, edges, out);
}

// Round 6
// 1860.433 us; speedup vs baseline: 4.2041x; 4.2041x over previous
//
#include <hip/hip_runtime.h>
#include <hip/hip_bf16.h>
#include <math.h>

// Problem constants (match reference)
#define BB 4
#define PP 32768
#define TOPK 5000
#define NB 4096          // score buckets for ranking
#define NBK 20           // ceil(5000/256) candidate tiles
#define TBPI 210         // NBK*(NBK+1)/2 triangular tile pairs per image
#define BMW 160          // bitmap words per row (157 used, 160 for 16B align)

// ws layout (bytes). Total 3,600,256 <= 3,742,720 B PROVEN available (round 1
// passed with its guard at exactly 3,742,720).
// Phase 1 (ranking) buffers are dead after rank_topk; the per-image suppression
// BITMAP (5000 rows x 160 words = 3,200,000 B) aliases them. Images are
// processed sequentially through the bitmap: pair(b) -> solve(b).
#define NV_OFF     0u
#define NC_OFF     64u
#define CS_OFF     256u         // float[BB*TOPK]  = 80,000
#define CB_OFF     80256u       // float4[BB*TOPK] = 320,000  (ends 400,256)
#define HIST_OFF   400256u      // uint[BB*NB] = 65,536
#define START_OFF  465792u      // uint[BB*NB] = 65,536
#define CNT_OFF    531328u      // uint[BB*NB] = 65,536
#define GIDX_OFF   596864u      // uint[BB*PP] = 524,288
#define GSC_OFF    1121152u     // float[BB*PP]= 524,288   (ends 1,645,440)
#define BM_OFF     400256u      // uint[TOPK*BMW] = 3,200,000 (ends 3,600,256)
#define WS_NEEDED  3600256u

__global__ __launch_bounds__(256) void score_hist_kernel(
    const float2* __restrict__ conf, unsigned* __restrict__ hist)
{
    int i = blockIdx.x * 256 + threadIdx.x;
    if (i >= BB * PP) return;
    int b = i >> 15;
    float s = conf[i].y;
    if (s > 0.05f) {
        int bk = (int)(s * 4096.0f);
        bk = bk < 0 ? 0 : (bk > NB - 1 ? NB - 1 : bk);
        atomicAdd(&hist[b * NB + bk], 1u);
    }
}

__global__ __launch_bounds__(256) void scan_hist_kernel(
    const unsigned* __restrict__ hist, unsigned* __restrict__ start,
    int* __restrict__ nvalid, int* __restrict__ ncand)
{
    int b = blockIdx.x;
    int t = threadIdx.x;
    __shared__ unsigned sums[256];
    unsigned local[16];
    unsigned s = 0;
    const unsigned* hb = hist + b * NB;
    #pragma unroll
    for (int k = 0; k < 16; k++) {
        unsigned v = hb[t * 16 + k];
        local[k] = s;
        s += v;
    }
    sums[t] = s;
    __syncthreads();
    for (int off = 1; off < 256; off <<= 1) {
        unsigned v = (t >= off) ? sums[t - off] : 0u;
        __syncthreads();
        sums[t] += v;
        __syncthreads();
    }
    unsigned excl = sums[t] - s;
    unsigned* sb = start + b * NB;
    #pragma unroll
    for (int k = 0; k < 16; k++) sb[t * 16 + k] = excl + local[k];
    if (t == 255) {
        nvalid[b] = (int)sums[255];
        ncand[b] = sums[255] < (unsigned)TOPK ? (int)sums[255] : TOPK;
    }
}

__global__ __launch_bounds__(256) void scatter_group_kernel(
    const float2* __restrict__ conf, const unsigned* __restrict__ start,
    unsigned* __restrict__ cnt, unsigned* __restrict__ gidx,
    float* __restrict__ gscore)
{
    int i = blockIdx.x * 256 + threadIdx.x;
    if (i >= BB * PP) return;
    int b = i >> 15;
    int p = i & (PP - 1);
    float s = conf[i].y;
    if (s > 0.05f) {
        int bk = (int)(s * 4096.0f);
        bk = bk < 0 ? 0 : (bk > NB - 1 ? NB - 1 : bk);
        unsigned o = atomicAdd(&cnt[b * NB + bk], 1u);
        unsigned pos = start[b * NB + bk] + o;
        gidx[b * PP + pos] = (unsigned)p;
        gscore[b * PP + pos] = s;
    }
}

// Exact stable rank (bucket base + within-bucket compare); decode the box
// with the identical fp expressions proven absmax-0.0 in rounds 1/5.
__global__ __launch_bounds__(256) void rank_topk_kernel(
    const unsigned* __restrict__ gidx, const float* __restrict__ gscore,
    const unsigned* __restrict__ start, const unsigned* __restrict__ hist,
    const int* __restrict__ nvalid, const float4* __restrict__ loc,
    const float4* __restrict__ prior,
    float* __restrict__ cs, float4* __restrict__ cb)
{
#pragma clang fp contract(off)
    int i = blockIdx.x * 256 + threadIdx.x;
    if (i >= BB * PP) return;
    int b = i >> 15;
    int pos = i & (PP - 1);
    int nv = nvalid[b];
    if (pos >= nv) return;
    float s = gscore[b * PP + pos];
    unsigned p = gidx[b * PP + pos];
    int bk = (int)(s * 4096.0f);
    bk = bk < 0 ? 0 : (bk > NB - 1 ? NB - 1 : bk);
    unsigned st = start[b * NB + bk];
    unsigned c = hist[b * NB + bk];
    unsigned rank = (unsigned)nv - st - c;   // strictly-higher buckets
    const float* gs = gscore + b * PP + st;
    const unsigned* gi = gidx + b * PP + st;
    for (unsigned k = 0; k < c; k++) {
        float sk = gs[k];
        unsigned pk = gi[k];
        if (sk > s || (sk == s && pk < p)) rank++;   // stable descending
    }
    if (rank < (unsigned)TOPK) {
        float4 l = loc[b * PP + (int)p];
        float4 pr = prior[p];
        float cx = pr.x + (l.x * 0.1f) * pr.z;
        float cy = pr.y + (l.y * 0.1f) * pr.w;
        float w = pr.z * expf(l.z * 0.2f);
        float h = pr.w * expf(l.w * 0.2f);
        float4 bx;
        bx.x = cx - 0.5f * w;
        bx.y = cy - 0.5f * h;
        bx.z = cx + 0.5f * w;
        bx.w = cy + 0.5f * h;
        cs[b * TOPK + rank] = s;
        cb[(size_t)b * TOPK + rank] = bx;
    }
}

// Dense suppression bitmap for ONE image: row i, bit j (j<i) set iff
// IoU(j,i) > 0.3 with the reference's exact fp ops. No atomics.
// Row i has words 0..(i>>5) defined (diagonal tile zeroes bits j>=i).
__global__ __launch_bounds__(256) void bitmap_pair_kernel(
    const float4* __restrict__ cb, const int* __restrict__ ncand,
    int img, unsigned* __restrict__ bitmap)
{
#pragma clang fp contract(off)
    int t_ = blockIdx.x;
    int bi = (int)((sqrtf(8.0f * (float)t_ + 1.0f) - 1.0f) * 0.5f);
    while ((bi + 1) * (bi + 2) / 2 <= t_) bi++;
    while (bi * (bi + 1) / 2 > t_) bi--;
    int bj = t_ - bi * (bi + 1) / 2;

    const float4* cbb = cb + (size_t)img * TOPK;

    __shared__ float4 jb[256];
    __shared__ float ja[256];
    int tid = threadIdx.x;
    int jg = bj * 256 + tid;
    if (jg < TOPK) {
        float4 v = cbb[jg];
        jb[tid] = v;
        ja[tid] = (v.z - v.x) * (v.w - v.y);
    }
    __syncthreads();

    int i = bi * 256 + tid;
    if (i >= TOPK) return;
    float4 bx = cbb[i];
    float areaI = (bx.z - bx.x) * (bx.w - bx.y);
    bool diag = (bi == bj);

    unsigned wds[8];
    #pragma unroll
    for (int w8 = 0; w8 < 8; w8++) {
        unsigned m = 0u;
        int jb0 = w8 * 32;
        for (int k = 0; k < 32; k++) {
            int jl = jb0 + k;
            int j = bj * 256 + jl;
            if (diag && j >= i) break;       // strict lower triangle
            float4 c = jb[jl];
            float iw = fminf(bx.z, c.z) - fmaxf(bx.x, c.x);
            iw = fmaxf(iw, 0.0f);
            float ih = fminf(bx.w, c.w) - fmaxf(bx.y, c.y);
            ih = fmaxf(ih, 0.0f);
            float inter = iw * ih;
            float uni = (ja[jl] + areaI) - inter;   // area[j]+area[i]-inter
            if (inter / uni > 0.3f) m |= (1u << k); // NaN -> false
        }
        wds[w8] = m;
    }
    uint4* r4 = (uint4*)(bitmap + (size_t)i * BMW + bj * 8);
    r4[0] = make_uint4(wds[0], wds[1], wds[2], wds[3]);
    r4[1] = make_uint4(wds[4], wds[5], wds[6], wds[7]);
}

// Fixpoint greedy-NMS solve on the bitmap for ONE image, then compact+write.
// Snapshot semantics per round: decisions read pK/pU (previous state), write
// kept/undec via LDS atomics. The min undecided index always decides =>
// guaranteed progress; result equals sequential greedy NMS.
__global__ __launch_bounds__(1024) void solve_bitmap_kernel(
    const float* __restrict__ cs, const float4* __restrict__ cb,
    const int* __restrict__ ncand, int img,
    const unsigned* __restrict__ bitmap, float* __restrict__ out)
{
    int t = threadIdx.x;
    int nc = ncand[img];
    __shared__ unsigned kept[BMW], undec[BMW], pK[BMW], pU[BMW];
    __shared__ unsigned pref[BMW];
    __shared__ int nundec;

    for (int w = t; w < BMW; w += 1024) {
        int lo = w * 32;
        unsigned m = 0u;
        if (lo + 32 <= nc) m = 0xffffffffu;
        else if (lo < nc) m = (1u << (nc - lo)) - 1u;
        undec[w] = m;
        kept[w] = 0u;
    }
    if (t == 0) nundec = nc;
    __syncthreads();

    while (true) {
        for (int w = t; w < BMW; w += 1024) { pK[w] = kept[w]; pU[w] = undec[w]; }
        __syncthreads();
        for (int i = t; i < nc; i += 1024) {
            if ((pU[i >> 5] >> (i & 31)) & 1u) {
                const unsigned* row = bitmap + (size_t)i * BMW;
                int nw = (i >> 5) + 1;       // words beyond are undefined/zero
                unsigned d = 0u, bl = 0u;
                for (int w = 0; w < nw; w++) {
                    unsigned r = row[w];
                    d |= r & pK[w];
                    bl |= r & pU[w];
                }
                if (d) {                      // an earlier kept box suppresses i
                    atomicAnd(&undec[i >> 5], ~(1u << (i & 31)));
                    atomicSub(&nundec, 1);
                } else if (!bl) {             // all earlier overlapping decided dead
                    atomicOr(&kept[i >> 5], 1u << (i & 31));
                    atomicAnd(&undec[i >> 5], ~(1u << (i & 31)));
                    atomicSub(&nundec, 1);
                }
            }
        }
        __syncthreads();
        if (nundec == 0) break;               // uniform: read after barrier
    }

    __syncthreads();
    if (t == 0) {
        unsigned s = 0;
        for (int w = 0; w < BMW; w++) { pref[w] = s; s += __popc(kept[w]); }
    }
    __syncthreads();

    const float* csb = cs + img * TOPK;
    const float4* cbb = cb + (size_t)img * TOPK;
    float* outb = out + ((size_t)img * 2 + 1) * TOPK * 5;
    for (int i = t; i < nc; i += 1024) {
        unsigned kw = kept[i >> 5];
        if ((kw >> (i & 31)) & 1u) {
            unsigned pos = pref[i >> 5] + __popc(kw & ((1u << (i & 31)) - 1u));
            float4 bx = cbb[i];
            float* row = outb + (size_t)pos * 5;
            row[0] = csb[i];
            row[1] = bx.x;
            row[2] = bx.y;
            row[3] = bx.z;
            row[4] = bx.w;
        }
    }
}

extern "C" void kernel_launch(void* const* d_in, const int* in_sizes, int n_in,
                              void* d_out, int out_size, void* d_ws, size_t ws_size,
                              hipStream_t stream) {
    if (ws_size < WS_NEEDED) return;  // fail loudly rather than corrupt

    const float4* loc = (const float4*)d_in[0];
    const float2* conf = (const float2*)d_in[1];
    const float4* prior = (const float4*)d_in[2];
    float* out = (float*)d_out;

    char* ws = (char*)d_ws;
    int* nvalid = (int*)(ws + NV_OFF);
    int* ncand = (int*)(ws + NC_OFF);
    float* cs = (float*)(ws + CS_OFF);
    float4* cb = (float4*)(ws + CB_OFF);
    unsigned* hist = (unsigned*)(ws + HIST_OFF);
    unsigned* start = (unsigned*)(ws + START_OFF);
    unsigned* cnt = (unsigned*)(ws + CNT_OFF);
    unsigned* gidx = (unsigned*)(ws + GIDX_OFF);
    float* gscore = (float*)(ws + GSC_OFF);
    unsigned* bitmap = (unsigned*)(ws + BM_OFF);  // aliases dead phase-1 bufs

    hipMemsetAsync(d_out, 0, (size_t)out_size * sizeof(float), stream);
    hipMemsetAsync(hist, 0, (size_t)BB * NB * sizeof(unsigned), stream);
    hipMemsetAsync(cnt, 0, (size_t)BB * NB * sizeof(unsigned), stream);

    int nblk = (BB * PP + 255) / 256;
    score_hist_kernel<<<nblk, 256, 0, stream>>>(conf, hist);
    scan_hist_kernel<<<BB, 256, 0, stream>>>(hist, start, nvalid, ncand);
    scatter_group_kernel<<<nblk, 256, 0, stream>>>(conf, start, cnt, gidx, gscore);
    rank_topk_kernel<<<nblk, 256, 0, stream>>>(gidx, gscore, start, hist, nvalid,
                                               loc, prior, cs, cb);
    for (int b = 0; b < BB; b++) {
        bitmap_pair_kernel<<<TBPI, 256, 0, stream>>>(cb, ncand, b, bitmap);
        solve_bitmap_kernel<<<1, 1024, 0, stream>>>(cs, cb, ncand, b, bitmap, out);
    }
}